// Round 5
// baseline (172.013 us; speedup 1.0000x reference)
//
#include <hip/hip_runtime.h>
#include <hip/hip_bf16.h>
#include <stdint.h>

#define BATCH 8192
#define DIM   512
#define TILE  128
#define BK    32
#define NITER (DIM / BK)              // 16
#define NT    (BATCH / TILE)          // 64 tiles per dim
#define NPAIR (NT * (NT + 1) / 2)     // 2080 upper-triangle tile pairs

// Fb = F_norm * sqrt(log2(e)/T) so acc = Fb·Fbᵀ is already log2-domain logits.
#define FEAT_SCALE 4.5398164f         // sqrt(1.4426950409/0.07)
#define LN2        0.69314718055994531f

typedef __attribute__((ext_vector_type(8))) short short8;
typedef __attribute__((ext_vector_type(4))) float f32x4;

__device__ __forceinline__ void gld_lds16(const void* g, void* l) {
  __builtin_amdgcn_global_load_lds(
      (__attribute__((address_space(1))) void*)(uintptr_t)g,
      (__attribute__((address_space(3))) void*)(uintptr_t)l,
      16, 0, 0);
}

// ---------------------------------------------------------------------------
// Kernel 1: row-normalize fp32 -> bf16 * FEAT_SCALE. One wave per row.
// Also zeroes rowsum and the done-counter used by the fused finalize.
// ---------------------------------------------------------------------------
__global__ __launch_bounds__(256) void normalize_bf16(
    const float* __restrict__ x, __hip_bfloat16* __restrict__ o,
    float* __restrict__ rowsum, int* __restrict__ doneCount) {
  const int wv = threadIdx.x >> 6, lane = threadIdx.x & 63;
  const int row = blockIdx.x * 4 + wv;
  if (lane == 0) rowsum[row] = 0.0f;
  if (blockIdx.x == 0 && threadIdx.x == 0) *doneCount = 0;
  const float4* xr = (const float4*)(x + (size_t)row * DIM);
  const float4 v0 = xr[lane];
  const float4 v1 = xr[lane + 64];
  float ss = v0.x * v0.x + v0.y * v0.y + v0.z * v0.z + v0.w * v0.w +
             v1.x * v1.x + v1.y * v1.y + v1.z * v1.z + v1.w * v1.w;
#pragma unroll
  for (int m = 32; m > 0; m >>= 1) ss += __shfl_xor(ss, m, 64);
  const float inv = FEAT_SCALE / fmaxf(sqrtf(ss), 1e-12f);
  ushort4 p0, p1;
  p0.x = __bfloat16_as_ushort(__float2bfloat16(v0.x * inv));
  p0.y = __bfloat16_as_ushort(__float2bfloat16(v0.y * inv));
  p0.z = __bfloat16_as_ushort(__float2bfloat16(v0.z * inv));
  p0.w = __bfloat16_as_ushort(__float2bfloat16(v0.w * inv));
  p1.x = __bfloat16_as_ushort(__float2bfloat16(v1.x * inv));
  p1.y = __bfloat16_as_ushort(__float2bfloat16(v1.y * inv));
  p1.z = __bfloat16_as_ushort(__float2bfloat16(v1.z * inv));
  p1.w = __bfloat16_as_ushort(__float2bfloat16(v1.w * inv));
  ushort4* orow = (ushort4*)(o + (size_t)row * DIM);
  orow[lane]      = p0;
  orow[lane + 64] = p1;
}

// ---------------------------------------------------------------------------
// Kernel 2: symmetric 128x128 bf16 MFMA tiles, upper triangle, natural order.
// Ping-pong double-buffered K-loop (BK=32, 16 iters, full unroll): prefetch
// gld_lds for iter k+1 issues BEFORE iter k's ds_read/MFMA, so the barrier's
// vmcnt(0) drain is covered by ~300 cyc of compute instead of exposing raw
// L2 latency every iteration (round-4 structure drained at issue).
// Epilogue: exp2 (log2-domain acc) -> LDS transpose reduce (overlaid on dead
// staging buffer) -> one global atomic per row-half; col sums via butterfly.
// Finalize fused: last block (device-scope done counter) computes the loss.
// ---------------------------------------------------------------------------
__global__ __launch_bounds__(256, 4) void sim_lse_kernel(
    const __hip_bfloat16* __restrict__ F, float* __restrict__ rowsum,
    float* __restrict__ possim, int* __restrict__ doneCount,
    float* __restrict__ out) {
  __shared__ __hip_bfloat16 smem[2 * TILE * BK * 2];  // 2 buffers x (A 8K + B 8K)
  __shared__ float colAcc[TILE];
  __shared__ int lastFlag;

  const int t = blockIdx.x;
  int by = (int)((129.0f - sqrtf(129.0f * 129.0f - 8.0f * (float)t)) * 0.5f);
  if (by > NT - 1) by = NT - 1;
  if (by < 0) by = 0;
  while ((by + 1) * (129 - (by + 1)) / 2 <= t) ++by;
  while (by * (129 - by) / 2 > t) --by;
  const int bx = by + (t - by * (129 - by) / 2);
  const bool diagTile = (bx == by);

  const int rowBase = by * TILE;
  const int colBase = bx * TILE;

  const int tid   = threadIdx.x;
  const int lane  = tid & 63;
  const int wv    = tid >> 6;
  const int waveM = wv >> 1;
  const int waveN = wv & 1;
  const int quad  = lane >> 4;
  const int l15   = lane & 15;

  if (tid < TILE) colAcc[tid] = 0.0f;

  f32x4 acc[4][4] = {};

  // --- staging: per buffer, tile = 16 chunks of 16 rows (1 KB each);
  // wave wv stages chunks {2wv, 2wv+1} of A and of B. 4 gld per wave/iter.
  const int sb   = lane & 3;                    // 16B slot within 64B row
  const int r16  = lane >> 2;                   // row within chunk
  const __hip_bfloat16* gA[2];
  const __hip_bfloat16* gB[2];
  int ldsAoff[2], ldsBoff[2];
#pragma unroll
  for (int c = 0; c < 2; ++c) {
    const int sRow = wv * 32 + c * 16 + r16;
    const int g = sb ^ ((sRow >> 1) & 3);       // swizzled logical k-block
    gA[c] = F + (size_t)(rowBase + sRow) * DIM + g * 8;
    gB[c] = F + (size_t)(colBase + sRow) * DIM + g * 8;
    ldsAoff[c] = (wv * 2 + c) * 1024;
    ldsBoff[c] = 8192 + (wv * 2 + c) * 1024;
  }

  // --- fragment LDS offsets within a buffer
  int aOff[4], bOff[4];
#pragma unroll
  for (int i = 0; i < 4; ++i) {
    const int Ra = waveM * 64 + i * 16 + l15;
    aOff[i] = Ra * 64 + (quad ^ ((Ra >> 1) & 3)) * 16;
    const int Rb = waveN * 64 + i * 16 + l15;
    bOff[i] = 8192 + Rb * 64 + (quad ^ ((Rb >> 1) & 3)) * 16;
  }
  char* sbase = (char*)smem;

  // prologue: fill buffer 0
#pragma unroll
  for (int c = 0; c < 2; ++c) {
    gld_lds16(gA[c], sbase + ldsAoff[c]);
    gld_lds16(gB[c], sbase + ldsBoff[c]);
  }
  __syncthreads();

#pragma unroll
  for (int it = 0; it < NITER; ++it) {
    const int cur = (it & 1) * 16384;
    const int nxt = ((it + 1) & 1) * 16384;
    if (it + 1 < NITER) {
      const int k0 = (it + 1) * BK;
#pragma unroll
      for (int c = 0; c < 2; ++c) {
        gld_lds16(gA[c] + k0, sbase + nxt + ldsAoff[c]);
        gld_lds16(gB[c] + k0, sbase + nxt + ldsBoff[c]);
      }
    }
    short8 a[4], b[4];
#pragma unroll
    for (int i = 0; i < 4; ++i) {
      a[i] = *(const short8*)(sbase + cur + aOff[i]);
      b[i] = *(const short8*)(sbase + cur + bOff[i]);
    }
#pragma unroll
    for (int mi = 0; mi < 4; ++mi)
#pragma unroll
      for (int ni = 0; ni < 4; ++ni)
        acc[mi][ni] =
            __builtin_amdgcn_mfma_f32_16x16x32_bf16(a[mi], b[ni], acc[mi][ni], 0, 0, 0);
    __syncthreads();   // publishes prefetch(it+1), protects buf reuse
  }

  // --- epilogue ---
  float* redBuf = (float*)smem;        // staging dead; 17408 B used
  f32x4 rsumv[4] = {};
  float colpart[4] = {0.0f, 0.0f, 0.0f, 0.0f};

  if (diagTile) {
#pragma unroll
    for (int mi = 0; mi < 4; ++mi)
#pragma unroll
      for (int ni = 0; ni < 4; ++ni)
#pragma unroll
        for (int r = 0; r < 4; ++r) {
          const int rl = waveM * 64 + mi * 16 + quad * 4 + r;
          const int cl = waveN * 64 + ni * 16 + l15;
          rsumv[mi][r] += (cl == rl) ? 0.0f : exp2f(acc[mi][ni][r]);
        }
  } else {
    const bool hasPos = (bx == by + 32);
#pragma unroll
    for (int mi = 0; mi < 4; ++mi)
#pragma unroll
      for (int ni = 0; ni < 4; ++ni)
#pragma unroll
        for (int r = 0; r < 4; ++r) {
          const float s = acc[mi][ni][r];
          const float e = exp2f(s);
          rsumv[mi][r] += e;
          colpart[ni] += e;
          if (hasPos) {
            const int rl = waveM * 64 + mi * 16 + quad * 4 + r;
            const int cl = waveN * 64 + ni * 16 + l15;
            if (cl == rl) {
              const int gi = rowBase + rl;
              possim[gi] = s;
              possim[gi + 4096] = s;
            }
          }
        }
  }

  {
    float* wbase = redBuf + ((waveN * 2 + waveM) * 16 + l15) * 68 + quad * 4;
#pragma unroll
    for (int mi = 0; mi < 4; ++mi)
      *(f32x4*)(wbase + mi * 16) = rsumv[mi];
  }

  if (!diagTile) {
#pragma unroll
    for (int ni = 0; ni < 4; ++ni) {
      float c = colpart[ni];
      c += __shfl_xor(c, 16, 64);
      c += __shfl_xor(c, 32, 64);
      if (quad == 0) atomicAdd(&colAcc[waveN * 64 + ni * 16 + l15], c);
    }
  }
  __syncthreads();

  {
    const int wn = tid >> 7, r = tid & 127;
    const int strip = r >> 6, rl = r & 63;
    const float* base = redBuf + ((wn * 2 + strip) * 16) * 68 + rl;
    float s = 0.0f;
#pragma unroll
    for (int j = 0; j < 16; ++j) s += base[j * 68];
    atomicAdd(&rowsum[rowBase + r], s);
  }
  if (tid < TILE && !diagTile)
    atomicAdd(&rowsum[colBase + tid], colAcc[tid]);

  // --- fused finalize: last block computes the loss ---
  __syncthreads();                 // all this block's atomics drained (vmcnt)
  if (tid == 0) {
    __threadfence();               // release our writes
    const int prev = atomicAdd(doneCount, 1);
    lastFlag = (prev == NPAIR - 1) ? 1 : 0;
  }
  __syncthreads();
  if (lastFlag) {
    __threadfence();               // acquire: see all blocks' writes
    volatile const float* rs = rowsum;
    volatile const float* ps = possim;
    float acc2 = 0.0f;
    for (int i = tid; i < BATCH; i += 256)
      acc2 += __logf(rs[i]) - ps[i] * LN2;
#pragma unroll
    for (int m = 32; m > 0; m >>= 1) acc2 += __shfl_xor(acc2, m, 64);
    if (lane == 0) redBuf[wv] = acc2;
    __syncthreads();
    if (tid == 0)
      out[0] = (redBuf[0] + redBuf[1] + redBuf[2] + redBuf[3]) *
               (1.0f / (float)BATCH);
  }
}

extern "C" void kernel_launch(void* const* d_in, const int* in_sizes, int n_in,
                              void* d_out, int out_size, void* d_ws, size_t ws_size,
                              hipStream_t stream) {
  const float* x = (const float*)d_in[0];
  float* out = (float*)d_out;

  __hip_bfloat16* Fb = (__hip_bfloat16*)d_ws;
  float* rowsum = (float*)((char*)d_ws + (size_t)BATCH * DIM * sizeof(__hip_bfloat16));
  float* possim = rowsum + BATCH;
  int* doneCount = (int*)(possim + BATCH);

  normalize_bf16<<<BATCH / 4, 256, 0, stream>>>(x, Fb, rowsum, doneCount);
  sim_lse_kernel<<<NPAIR, 256, 0, stream>>>(Fb, rowsum, possim, doneCount, out);
}